// Round 5
// baseline (1150.606 us; speedup 1.0000x reference)
//
#include <hip/hip_runtime.h>
#include <math.h>

#define NB 4
#define TT 2048
#define CC 2048
#define HH 16
#define DD 128
#define N3 6144
#define MM 8192   // NB*TT
#define BH 64     // NB*HH

typedef short bf8 __attribute__((ext_vector_type(8)));        // 8 bf16 (4 VGPR)
typedef float f32x4 __attribute__((ext_vector_type(4)));
typedef float f32x16 __attribute__((ext_vector_type(16)));
typedef unsigned short u16x8 __attribute__((ext_vector_type(8)));
typedef unsigned short u16;

constexpr float SCALE_QK  = 0.08838834764831843f;   // 1/sqrt(128)
constexpr float NEG_ALPHA = -0.20503692777194262f;  // -2*ln(500000)/128

__device__ __forceinline__ u16 f2bf(float x) {                 // RTNE f32->bf16
    unsigned int u = __float_as_uint(x);
    u += 0x7fffu + ((u >> 16) & 1u);
    return (u16)(u >> 16);
}
__device__ __forceinline__ float bf2f(u16 h) { return __uint_as_float(((unsigned int)h) << 16); }

__device__ __forceinline__ void gl_lds16(const u16* g, u16* l) {
    __builtin_amdgcn_global_load_lds(reinterpret_cast<const unsigned int*>(g),
                                     reinterpret_cast<unsigned int*>(l), 16, 0, 0);
}
__device__ __forceinline__ f32x4 MFMA(bf8 a, bf8 b, f32x4 c) {
    return __builtin_amdgcn_mfma_f32_16x16x32_bf16(a, b, c, 0, 0, 0);
}
__device__ __forceinline__ f32x16 MFMA32(bf8 a, bf8 b, f32x16 c) {
    return __builtin_amdgcn_mfma_f32_32x32x16_bf16(a, b, c, 0, 0, 0);
}

#define BAR()    __builtin_amdgcn_s_barrier()
#define SCHED0() __builtin_amdgcn_sched_barrier(0)
#define WAIT_LGKM0() do { asm volatile("s_waitcnt lgkmcnt(0)" ::: "memory"); SCHED0(); } while (0)
#define WAIT_VM8()   do { asm volatile("s_waitcnt vmcnt(8)"   ::: "memory"); SCHED0(); } while (0)
#define WAIT_VM4()   do { asm volatile("s_waitcnt vmcnt(4)"   ::: "memory"); SCHED0(); } while (0)
#define WAIT_VM0()   do { asm volatile("s_waitcnt vmcnt(0)"   ::: "memory"); SCHED0(); } while (0)

// ---------------------------------------------------------------------------
// RoPE table: tab[t][p] = {cos, sin}(t * base^(-2p/128)), 2048 x 64 x 2 f32.
// ---------------------------------------------------------------------------
__global__ void rope_tab_k(float* __restrict__ tab) {
    int t = blockIdx.x, p = threadIdx.x;
    float inv = expf((float)p * NEG_ALPHA);
    float s, c;
    sincosf((float)t * inv, &s, &c);
    tab[(t * 64 + p) * 2]     = c;
    tab[(t * 64 + p) * 2 + 1] = s;
}

// ---------------------------------------------------------------------------
// Elementwise split fp32 -> bf16 hi + bf16 lo (same layout).
// ---------------------------------------------------------------------------
__global__ __launch_bounds__(256) void split_x_k(const float* __restrict__ X,
                                                 u16* __restrict__ H, u16* __restrict__ L) {
    size_t base = ((size_t)blockIdx.x * 256 + threadIdx.x) * 16;
    #pragma unroll
    for (int g = 0; g < 2; ++g) {
        u16x8 hv, lv;
        #pragma unroll
        for (int j = 0; j < 8; j += 4) {
            float4 a = *(const float4*)(X + base + g * 8 + j);
            float xs[4] = {a.x, a.y, a.z, a.w};
            #pragma unroll
            for (int q = 0; q < 4; ++q) {
                u16 h = f2bf(xs[q]);
                hv[j + q] = h;
                lv[j + q] = f2bf(xs[q] - bf2f(h));
            }
        }
        *(u16x8*)&H[base + g * 8] = hv;
        *(u16x8*)&L[base + g * 8] = lv;
    }
}

// ---------------------------------------------------------------------------
// Transpose + bf16 (hi only): W[Kd][Nd] fp32 -> OH[Nd][Kd] bf16.
// ---------------------------------------------------------------------------
__global__ __launch_bounds__(256) void splitT_h(const float* __restrict__ W,
                                                u16* __restrict__ OH,
                                                int Kd, int Nd) {
    __shared__ float tile[64][68];
    int k0 = blockIdx.x * 64, n0 = blockIdx.y * 64;
    {
        int r = threadIdx.x >> 2, cg = threadIdx.x & 3;
        const float* src = W + (size_t)(k0 + r) * Nd + n0 + cg * 16;
        #pragma unroll
        for (int j = 0; j < 4; ++j)
            *(float4*)&tile[r][cg * 16 + j * 4] = *(const float4*)(src + j * 4);
    }
    __syncthreads();
    int nl = threadIdx.x >> 2, kg = threadIdx.x & 3;
    u16x8 hv[2];
    #pragma unroll
    for (int j = 0; j < 16; ++j)
        hv[j >> 3][j & 7] = f2bf(tile[kg * 16 + j][nl]);
    size_t off = (size_t)(n0 + nl) * Kd + k0 + kg * 16;
    *(u16x8*)&OH[off]     = hv[0];
    *(u16x8*)&OH[off + 8] = hv[1];
}

// ---------------------------------------------------------------------------
// 8-phase 256x256 split-bf16 GEMM on 32x32x16 MFMA, 2-pass: C = (Ah+Al)*Bh.
// Logical K = 4096 (2 A-planes x K=2048), BK=64, NKT=64 K-tiles.
// 512 thr = 8 waves (2M x 4N), per-wave 128x64 out = 4x2 32x32 tiles,
// acc[4][2] f32x16. A-frag: lane l -> row=l&31, k=(l>>5)*8..+8 per K=16 step.
// C/D: col=lane&31, row=(reg&3)+8*(reg>>2)+4*(lane>>5)  [guide m74/m101].
// LDS: A/B double-buffered 128-row halves, 4 x 16KB = 128 KiB, chunk-XOR
// swizzle via pre-swizzled global source. Counted vmcnt(4) at tile boundary.
// MODE 0: QKV epilogue (RoPE; Q hi/lo planes, K bf16, V transposed [bh][d][t]).
// MODE 1: plain fp32 store.
// ---------------------------------------------------------------------------
template<int MODE>
__device__ __forceinline__ void gemm32_body(
    const u16* __restrict__ Ahp, const u16* __restrict__ Alp,
    const u16* __restrict__ Bhp,
    u16* __restrict__ Qh, u16* __restrict__ Ql,
    u16* __restrict__ Kbo, u16* __restrict__ Vto,
    const float* __restrict__ tab, float* __restrict__ Out,
    int bx, int by)
{
    __shared__ u16 SM[66048];          // 129 KiB (GEMM uses first 65536)

    const int tid = threadIdx.x;
    const int w = tid >> 6, ln = tid & 63;
    const int l31 = ln & 31, l5 = ln >> 5;
    const int wr = w >> 2, wc = w & 3;          // 2 x 4 wave grid
    const int m0 = bx * 256, n0 = by * 256;
    const int NKT = 64;

    f32x16 acc[4][2];
    #pragma unroll
    for (int i = 0; i < 4; ++i)
        #pragma unroll
        for (int j = 0; j < 2; ++j)
            #pragma unroll
            for (int r = 0; r < 16; ++r) acc[i][j][r] = 0.f;

    // ---- staging: stream s = 4*tau + {0:A0,1:A1,2:B0,3:B1}, tau = K-tile ----
    auto stage = [&](int s) {
        if (s >= 4 * NKT) return;
        const int tau = s >> 2, j = s & 3;
        const int c2 = tau & 1, op = j >> 1, hf = j & 1;
        const int tdiv = tau >> 5, tmod = tau & 31;
        const u16* plane;
        int row0;
        if (op == 0) { plane = tdiv ? Alp : Ahp; row0 = m0 + hf * 128; }
        else         { plane = Bhp;              row0 = n0 + hf * 128; }
        u16* dst = SM + (op ? 32768 : 0) + (c2 * 2 + hf) * 8192;
        #pragma unroll
        for (int i = 0; i < 2; ++i) {
            int L = i * 8192 + tid * 16;     // byte offset within 16KB half
            int r = L >> 7;                  // row (128 B = 64 bf16 per row)
            int c = (L >> 4) & 7;
            int cs = c ^ (r & 7);            // pre-swizzled source chunk
            gl_lds16(plane + (size_t)(row0 + r) * 2048 + tmod * 64 + cs * 8,
                     dst + (L >> 1));
        }
    };

    #pragma unroll
    for (int s = 0; s < 6; ++s) stage(s);
    WAIT_VM4();
    BAR();

    bf8 aF[4][4], bF[2][4];
    const int brow0 = (wc & 1) * 64;

    for (int t = 0; t < NKT; ++t) {
        const int c2 = t & 1;
        const u16* Ab = SM + (c2 * 2 + wr) * 8192;
        const u16* Bb = SM + 32768 + (c2 * 2 + (wc >> 1)) * 8192;

        // ---------- P1: read aF[0:1], bF[0]; stage t+1.B0 ----------
        #pragma unroll
        for (int mt = 0; mt < 2; ++mt) {
            int rl = mt * 32 + l31, s7 = rl & 7;
            #pragma unroll
            for (int ks = 0; ks < 4; ++ks)
                aF[mt][ks] = *(const bf8*)&Ab[rl * 64 + (((ks * 2 + l5) ^ s7)) * 8];
        }
        {
            int rl = brow0 + l31, s7 = rl & 7;
            #pragma unroll
            for (int ks = 0; ks < 4; ++ks)
                bF[0][ks] = *(const bf8*)&Bb[rl * 64 + (((ks * 2 + l5) ^ s7)) * 8];
        }
        stage(4 * t + 6);
        BAR(); WAIT_LGKM0();
        __builtin_amdgcn_s_setprio(1);
        #pragma unroll
        for (int mt = 0; mt < 2; ++mt)
            #pragma unroll
            for (int ks = 0; ks < 4; ++ks)
                acc[mt][0] = MFMA32(aF[mt][ks], bF[0][ks], acc[mt][0]);
        __builtin_amdgcn_s_setprio(0);
        BAR();

        // ---------- P2: read aF[2:3]; stage t+1.B1 ----------
        #pragma unroll
        for (int mt = 2; mt < 4; ++mt) {
            int rl = mt * 32 + l31, s7 = rl & 7;
            #pragma unroll
            for (int ks = 0; ks < 4; ++ks)
                aF[mt][ks] = *(const bf8*)&Ab[rl * 64 + (((ks * 2 + l5) ^ s7)) * 8];
        }
        stage(4 * t + 7);
        BAR(); WAIT_LGKM0();
        __builtin_amdgcn_s_setprio(1);
        #pragma unroll
        for (int mt = 2; mt < 4; ++mt)
            #pragma unroll
            for (int ks = 0; ks < 4; ++ks)
                acc[mt][0] = MFMA32(aF[mt][ks], bF[0][ks], acc[mt][0]);
        __builtin_amdgcn_s_setprio(0);
        BAR();

        // ---------- P3: read bF[1]; stage t+2.A0 ----------
        {
            int rl = brow0 + 32 + l31, s7 = rl & 7;
            #pragma unroll
            for (int ks = 0; ks < 4; ++ks)
                bF[1][ks] = *(const bf8*)&Bb[rl * 64 + (((ks * 2 + l5) ^ s7)) * 8];
        }
        stage(4 * t + 8);
        BAR(); WAIT_LGKM0();
        __builtin_amdgcn_s_setprio(1);
        #pragma unroll
        for (int mt = 0; mt < 2; ++mt)
            #pragma unroll
            for (int ks = 0; ks < 4; ++ks)
                acc[mt][1] = MFMA32(aF[mt][ks], bF[1][ks], acc[mt][1]);
        __builtin_amdgcn_s_setprio(0);
        BAR();

        // ---------- P4: stage t+2.A1; boundary wait ----------
        stage(4 * t + 9);
        BAR();
        __builtin_amdgcn_s_setprio(1);
        #pragma unroll
        for (int mt = 2; mt < 4; ++mt)
            #pragma unroll
            for (int ks = 0; ks < 4; ++ks)
                acc[mt][1] = MFMA32(aF[mt][ks], bF[1][ks], acc[mt][1]);
        __builtin_amdgcn_s_setprio(0);
        if (t < NKT - 2)       { WAIT_VM4(); }
        else if (t == NKT - 2) { WAIT_VM0(); }
        BAR();
    }

    // ======================= epilogues =======================
    const int colbase = wc * 64 + l31;
    if (MODE == 1) {
        #pragma unroll
        for (int mt = 0; mt < 4; ++mt)
            #pragma unroll
            for (int nt = 0; nt < 2; ++nt) {
                int n = n0 + colbase + nt * 32;
                #pragma unroll
                for (int reg = 0; reg < 16; ++reg) {
                    int m = m0 + wr * 128 + mt * 32 + (reg & 3) + 8 * (reg >> 2) + 4 * l5;
                    Out[(size_t)m * CC + n] = acc[mt][nt][reg];
                }
            }
        return;
    }

    const int sec = n0 >> 11;                  // 0=q 1=k 2=v
    const int hh0 = (n0 >> 7) & 15;
    if (sec < 2) {
        #pragma unroll
        for (int mt = 0; mt < 4; ++mt)
            #pragma unroll
            for (int nt = 0; nt < 2; ++nt) {
                int nl = colbase + nt * 32;
                int h = hh0 + (nl >> 7), d = nl & 127;
                #pragma unroll
                for (int reg = 0; reg < 16; ++reg) {
                    int m = m0 + wr * 128 + mt * 32 + (reg & 3) + 8 * (reg >> 2) + 4 * l5;
                    int t = m & 2047, b = m >> 11;
                    float v = acc[mt][nt][reg];
                    float o = __shfl_xor(v, 1);
                    const float2 cs2 = *(const float2*)&tab[(((size_t)t << 6) + (d >> 1)) * 2];
                    float rv = (ln & 1) ? (v * cs2.x + o * cs2.y)
                                        : (v * cs2.x - o * cs2.y);
                    size_t off = (((size_t)(b * HH + h)) * TT + t) * DD + d;
                    if (sec == 0) {
                        rv *= SCALE_QK;
                        u16 hv = f2bf(rv);
                        Qh[off] = hv;
                        Ql[off] = f2bf(rv - bf2f(hv));
                    } else {
                        Kbo[off] = f2bf(rv);
                    }
                }
            }
    } else {
        // V: bf16, transpose to [bh][d][t] via LDS [256][258] u16.
        BAR();
        #pragma unroll
        for (int mt = 0; mt < 4; ++mt)
            #pragma unroll
            for (int nt = 0; nt < 2; ++nt) {
                int nl = colbase + nt * 32;
                #pragma unroll
                for (int reg = 0; reg < 16; ++reg) {
                    int tl = wr * 128 + mt * 32 + (reg & 3) + 8 * (reg >> 2) + 4 * l5;
                    SM[tl * 258 + nl] = f2bf(acc[mt][nt][reg]);
                }
            }
        BAR();
        int nl = tid >> 1, th = tid & 1;
        int head = hh0 + (nl >> 7), d = nl & 127;
        int b = m0 >> 11, t0 = m0 & 2047;
        size_t base = (((size_t)(b * HH + head)) * DD + d) * TT + t0 + th * 128;
        #pragma unroll
        for (int g = 0; g < 16; ++g) {
            u16x8 vv;
            #pragma unroll
            for (int j = 0; j < 8; ++j) vv[j] = SM[(th * 128 + g * 8 + j) * 258 + nl];
            *(u16x8*)&Vto[base + g * 8] = vv;
        }
    }
}

// XCD-swizzled wrappers (nwg % 8 == 0 -> simple bijective form).
__global__ __launch_bounds__(512, 2) void qkv_gemm32(
    const u16* __restrict__ Ahp, const u16* __restrict__ Alp,
    const u16* __restrict__ Bhp,
    u16* __restrict__ Qh, u16* __restrict__ Ql,
    u16* __restrict__ Kbo, u16* __restrict__ Vto,
    const float* __restrict__ tab)
{
    int bid = blockIdx.x;                       // 768 blocks
    int wg = (bid & 7) * 96 + (bid >> 3);
    gemm32_body<0>(Ahp, Alp, Bhp, Qh, Ql, Kbo, Vto, tab, nullptr,
                   wg & 31, wg >> 5);
}
__global__ __launch_bounds__(512, 2) void proj_gemm32(
    const u16* __restrict__ Ahp, const u16* __restrict__ Alp,
    const u16* __restrict__ Bhp, float* __restrict__ Out)
{
    int bid = blockIdx.x;                       // 256 blocks
    int wg = (bid & 7) * 32 + (bid >> 3);
    gemm32_body<1>(Ahp, Alp, Bhp, nullptr, nullptr, nullptr, nullptr,
                   nullptr, Out, wg & 31, wg >> 5);
}

// ---------------------------------------------------------------------------
// Flash attention: QBLK=128, KVBLK=64, 4 waves x 32 q-rows (unchanged).
// ---------------------------------------------------------------------------
__global__ __launch_bounds__(256, 2) void attn128(
    const u16* __restrict__ Qhp, const u16* __restrict__ Qlp,
    const u16* __restrict__ Kb,  const u16* __restrict__ Vt,
    u16* __restrict__ Yh, u16* __restrict__ Yl)
{
    // u16 index map: K0 @0, K1 @8192, V0 @16384, V1 @24576, Ps @32768 (+w*2048)
    __shared__ u16 SM[40960];   // 80 KiB

    const int tid = threadIdx.x;
    const int w = tid >> 6, ln = tid & 63;
    const int lo4 = ln & 15, hi4 = ln >> 4;
    const int bx = blockIdx.x;
    const int qt = (bx & 1) ? (15 - (bx >> 1)) : (bx >> 1);   // pair big+small
    const int bh = blockIdx.y;
    const int q0 = qt * 128;
    const int last = 2 * qt + 1;

    // ---- stage Q hi -> SM[0..16384), Q lo -> SM[16384..32768) ----
    const size_t qoff = ((size_t)bh * TT + q0) * DD;
    #pragma unroll
    for (int i = 0; i < 8; ++i) {
        int L = i * 4096 + tid * 16;
        int r = L >> 8, c = (L >> 4) & 15;
        int cs = c ^ (r & 7);
        gl_lds16(Qhp + qoff + r * DD + cs * 8, &SM[L >> 1]);
        gl_lds16(Qlp + qoff + r * DD + cs * 8, &SM[16384 + (L >> 1)]);
    }
    WAIT_VM0();
    BAR();
    bf8 qh[2][4], ql[2][4];
    #pragma unroll
    for (int mf = 0; mf < 2; ++mf) {
        int rq = w * 32 + mf * 16 + lo4, s7 = rq & 7;
        #pragma unroll
        for (int ks = 0; ks < 4; ++ks) {
            int ch = (ks * 4 + hi4) ^ s7;
            qh[mf][ks] = *(const bf8*)&SM[rq * 128 + ch * 8];
            ql[mf][ks] = *(const bf8*)&SM[16384 + rq * 128 + ch * 8];
        }
    }
    WAIT_LGKM0();
    BAR();

    auto stageKV = [&](int kt2, int buf) {
        const size_t koff = ((size_t)bh * TT + kt2 * 64) * DD;
        u16* kd = &SM[buf * 8192];
        #pragma unroll
        for (int i = 0; i < 4; ++i) {
            int L = i * 4096 + tid * 16;
            int r = L >> 8, c = (L >> 4) & 15, cs = c ^ (r & 7);
            gl_lds16(Kb + koff + r * DD + cs * 8, kd + (L >> 1));
        }
        const size_t voff = (size_t)bh * DD * TT + (size_t)kt2 * 64;
        u16* vd = &SM[16384 + buf * 8192];
        #pragma unroll
        for (int i = 0; i < 4; ++i) {
            int L = i * 4096 + tid * 16;
            int r = L >> 7, c = (L >> 4) & 7, cs = c ^ (r & 7);
            gl_lds16(Vt + voff + (size_t)r * TT + cs * 8, vd + (L >> 1));
        }
    };
    stageKV(0, 0);

    f32x4 O[2][8];
    #pragma unroll
    for (int mf = 0; mf < 2; ++mf)
        #pragma unroll
        for (int i = 0; i < 8; ++i) O[mf][i] = (f32x4){0.f, 0.f, 0.f, 0.f};
    float m_r[2][4], l_r[2][4];
    #pragma unroll
    for (int mf = 0; mf < 2; ++mf)
        #pragma unroll
        for (int r = 0; r < 4; ++r) { m_r[mf][r] = -1e30f; l_r[mf][r] = 0.f; }

    for (int kt = 0; kt <= last; ++kt) {
        const int cur = kt & 1;
        if (kt < last) { stageKV(kt + 1, cur ^ 1); WAIT_VM8(); }
        else           { WAIT_VM0(); }
        BAR();
        const u16* Kcur = &SM[cur * 8192];
        const u16* Vcur = &SM[16384 + cur * 8192];

        // ---- S = (Qh+Ql) K^T (scale folded into Q) ----
        f32x4 sf[2][4];
        #pragma unroll
        for (int nf = 0; nf < 4; ++nf) {
            f32x4 s0 = (f32x4){0.f, 0.f, 0.f, 0.f};
            f32x4 s1 = (f32x4){0.f, 0.f, 0.f, 0.f};
            int kr = nf * 16 + lo4, s7 = kr & 7;
            #pragma unroll
            for (int ks = 0; ks < 4; ++ks) {
                bf8 bb = *(const bf8*)&Kcur[kr * 128 + ((ks * 4 + hi4) ^ s7) * 8];
                s0 = MFMA(qh[0][ks], bb, s0);
                s0 = MFMA(ql[0][ks], bb, s0);
                s1 = MFMA(qh[1][ks], bb, s1);
                s1 = MFMA(ql[1][ks], bb, s1);
            }
            sf[0][nf] = s0; sf[1][nf] = s1;
        }
        if (kt >= 2 * qt) {   // diagonal tiles: causal mask
            #pragma unroll
            for (int mf = 0; mf < 2; ++mf)
                #pragma unroll
                for (int nf = 0; nf < 4; ++nf)
                    #pragma unroll
                    for (int r = 0; r < 4; ++r) {
                        int kg = kt * 64 + nf * 16 + lo4;
                        int qg = q0 + w * 32 + mf * 16 + hi4 * 4 + r;
                        if (kg > qg) sf[mf][nf][r] = -1e30f;
                    }
        }

        // ---- online softmax with defer-max (THR=0: bit-exact skip) ----
        #pragma unroll
        for (int mf = 0; mf < 2; ++mf) {
            float mx[4];
            #pragma unroll
            for (int r = 0; r < 4; ++r) {
                float m2 = fmaxf(fmaxf(sf[mf][0][r], sf[mf][1][r]),
                                 fmaxf(sf[mf][2][r], sf[mf][3][r]));
                m2 = fmaxf(m2, __shfl_xor(m2, 1));
                m2 = fmaxf(m2, __shfl_xor(m2, 2));
                m2 = fmaxf(m2, __shfl_xor(m2, 4));
                m2 = fmaxf(m2, __shfl_xor(m2, 8));
                mx[r] = m2;
            }
            float al[4] = {1.f, 1.f, 1.f, 1.f};
            bool grow = (mx[0] > m_r[mf][0]) || (mx[1] > m_r[mf][1]) ||
                        (mx[2] > m_r[mf][2]) || (mx[3] > m_r[mf][3]);
            if (__any(grow)) {
                #pragma unroll
                for (int r = 0; r < 4; ++r) {
                    float mn = fmaxf(m_r[mf][r], mx[r]);
                    al[r] = __expf(m_r[mf][r] - mn);
                    m_r[mf][r] = mn;
                }
                #pragma unroll
                for (int nf2 = 0; nf2 < 8; ++nf2)
                    #pragma unroll
                    for (int r = 0; r < 4; ++r) O[mf][nf2][r] *= al[r];
            }
            #pragma unroll
            for (int r = 0; r < 4; ++r) {
                float rs = 0.f;
                #pragma unroll
                for (int nf = 0; nf < 4; ++nf) {
                    float p = __expf(sf[mf][nf][r] - m_r[mf][r]);
                    sf[mf][nf][r] = p;
                    rs += p;
                }
                rs += __shfl_xor(rs, 1);
                rs += __shfl_xor(rs, 2);
                rs += __shfl_xor(rs, 4);
                rs += __shfl_xor(rs, 8);
                l_r[mf][r] = l_r[mf][r] * al[r] + rs;
            }
        }

        // ---- P -> bf16 -> per-wave swizzled LDS; then O += P V ----
        u16* pw = &SM[32768 + w * 2048];
        #pragma unroll
        for (int mf = 0; mf < 2; ++mf)
            #pragma unroll
            for (int r = 0; r < 4; ++r) {
                int row = mf * 16 + hi4 * 4 + r;
                int sw = (row & 7) << 3;
                #pragma unroll
                for (int nf = 0; nf < 4; ++nf)
                    pw[row * 64 + ((nf * 16 + lo4) ^ sw)] = f2bf(sf[mf][nf][r]);
            }
        bf8 pa[2][2];
        #pragma unroll
        for (int mf = 0; mf < 2; ++mf) {
            int rp = mf * 16 + lo4, s3 = rp & 7;
            pa[mf][0] = *(const bf8*)&pw[rp * 64 + ((hi4 ^ s3) * 8)];
            pa[mf][1] = *(const bf8*)&pw[rp * 64 + (((4 + hi4) ^ s3) * 8)];
        }
        #pragma unroll
        for (int nf2 = 0; nf2 < 8; ++nf2) {
            int vr = nf2 * 16 + lo4, s7 = vr & 7;
            #pragma unroll
            for (int ks = 0; ks < 2; ++ks) {
                bf8 vb = *(const bf8*)&Vcur[vr * 64 + ((ks * 4 + hi4) ^ s7) * 8];
                O[0][nf2] = MFMA(pa[0][ks], vb, O[0][nf2]);
                O[1][nf2] = MFMA(pa[1][ks], vb, O[1][nf2]);
            }
        }
        BAR();   // all reads of buf[cur] done before next prefetch overwrites
    }

    // ---- epilogue: y = O/l as bf16 hi/lo planes ----
    const int b = bh >> 4, h = bh & 15;
    #pragma unroll
    for (int mf = 0; mf < 2; ++mf)
        #pragma unroll
        for (int r = 0; r < 4; ++r) {
            float inv = 1.0f / l_r[mf][r];
            int t = q0 + w * 32 + mf * 16 + hi4 * 4 + r;
            size_t rowo = ((size_t)(b * TT + t)) * CC + h * DD;
            #pragma unroll
            for (int nf2 = 0; nf2 < 8; ++nf2) {
                float val = O[mf][nf2][r] * inv;
                u16 hv = f2bf(val);
                Yh[rowo + nf2 * 16 + lo4] = hv;
                Yl[rowo + nf2 * 16 + lo4] = f2bf(val - bf2f(hv));
            }
        }
}

// ---------------------------------------------------------------------------
extern "C" void kernel_launch(void* const* d_in, const int* in_sizes, int n_in,
                              void* d_out, int out_size, void* d_ws, size_t ws_size,
                              hipStream_t stream)
{
    const float* X     = (const float*)d_in[0];
    const float* Wqkv  = (const float*)d_in[1];
    const float* Wproj = (const float*)d_in[2];

    char* W = (char*)d_ws;
    float* tab = (float*)W;                                   //   1 MiB
    u16* Wqh = (u16*)(W + (1u << 20));                        //  24 MiB
    u16* Wph = Wqh + 12582912;                                //   8 MiB
    u16* Xh  = Wph + 4194304;                                 //  32 MiB
    u16* Xl  = Xh + 16777216;                                 //  32 MiB
    u16* Kb  = Xl + 16777216;                                 //  32 MiB
    u16* Vt  = Kb + 16777216;                                 //  32 MiB  (~161 MiB)

    u16* Qh = (u16*)d_out;          // parked in d_out (dead before proj writes)
    u16* Ql = Qh + 16777216;

    u16* Yh = Xh;   // y planes alias X planes (X dead after QKV gemm)
    u16* Yl = Xl;

    rope_tab_k<<<dim3(2048), 64, 0, stream>>>(tab);
    split_x_k<<<dim3(4096), 256, 0, stream>>>(X, Xh, Xl);
    splitT_h<<<dim3(32, 96), 256, 0, stream>>>(Wqkv, Wqh, 2048, 6144);
    splitT_h<<<dim3(32, 32), 256, 0, stream>>>(Wproj, Wph, 2048, 2048);

    qkv_gemm32<<<dim3(768), 512, 0, stream>>>(Xh, Xl, Wqh, Qh, Ql, Kb, Vt, tab);
    attn128<<<dim3(16, 64), 256, 0, stream>>>(Qh, Ql, Kb, Vt, Yh, Yl);
    proj_gemm32<<<dim3(256), 512, 0, stream>>>(Yh, Yl, Wph, (float*)d_out);
}

// Round 6
// 1001.685 us; speedup vs baseline: 1.1487x; 1.1487x over previous
//
#include <hip/hip_runtime.h>
#include <math.h>

#define NB 4
#define TT 2048
#define CC 2048
#define HH 16
#define DD 128
#define N3 6144
#define MM 8192   // NB*TT
#define BH 64     // NB*HH

typedef short bf8 __attribute__((ext_vector_type(8)));        // 8 bf16 (4 VGPR)
typedef float f32x4 __attribute__((ext_vector_type(4)));
typedef unsigned short u16x8 __attribute__((ext_vector_type(8)));
typedef unsigned short u16;

constexpr float SCALE_QK  = 0.08838834764831843f;   // 1/sqrt(128)
// Q-path scale with log2(e) folded in: softmax runs in exp2 domain.
constexpr float SCALE_Q2  = 0.08838834764831843f * 1.44269504088896f;
constexpr float NEG_ALPHA = -0.20503692777194262f;  // -2*ln(500000)/128

__device__ __forceinline__ u16 f2bf(float x) {                 // RTNE f32->bf16
    unsigned int u = __float_as_uint(x);
    u += 0x7fffu + ((u >> 16) & 1u);
    return (u16)(u >> 16);
}
__device__ __forceinline__ float bf2f(u16 h) { return __uint_as_float(((unsigned int)h) << 16); }

__device__ __forceinline__ void gl_lds16(const u16* g, u16* l) {
    __builtin_amdgcn_global_load_lds(reinterpret_cast<const unsigned int*>(g),
                                     reinterpret_cast<unsigned int*>(l), 16, 0, 0);
}
__device__ __forceinline__ f32x4 MFMA(bf8 a, bf8 b, f32x4 c) {
    return __builtin_amdgcn_mfma_f32_16x16x32_bf16(a, b, c, 0, 0, 0);
}

#define BAR()    __builtin_amdgcn_s_barrier()
#define SCHED0() __builtin_amdgcn_sched_barrier(0)
#define WAIT_LGKM0() do { asm volatile("s_waitcnt lgkmcnt(0)" ::: "memory"); SCHED0(); } while (0)
#define WAIT_VM8()   do { asm volatile("s_waitcnt vmcnt(8)"   ::: "memory"); SCHED0(); } while (0)
#define WAIT_VM4()   do { asm volatile("s_waitcnt vmcnt(4)"   ::: "memory"); SCHED0(); } while (0)
#define WAIT_VM0()   do { asm volatile("s_waitcnt vmcnt(0)"   ::: "memory"); SCHED0(); } while (0)

// ---------------------------------------------------------------------------
// RoPE table: tab[t][p] = {cos, sin}(t * base^(-2p/128)), 2048 x 64 x 2 f32.
// ---------------------------------------------------------------------------
__global__ void rope_tab_k(float* __restrict__ tab) {
    int t = blockIdx.x, p = threadIdx.x;
    float inv = expf((float)p * NEG_ALPHA);
    float s, c;
    sincosf((float)t * inv, &s, &c);
    tab[(t * 64 + p) * 2]     = c;
    tab[(t * 64 + p) * 2 + 1] = s;
}

// ---------------------------------------------------------------------------
// Elementwise split fp32 -> bf16 hi + bf16 lo (same layout).
// ---------------------------------------------------------------------------
__global__ __launch_bounds__(256) void split_x_k(const float* __restrict__ X,
                                                 u16* __restrict__ H, u16* __restrict__ L) {
    size_t base = ((size_t)blockIdx.x * 256 + threadIdx.x) * 16;
    #pragma unroll
    for (int g = 0; g < 2; ++g) {
        u16x8 hv, lv;
        #pragma unroll
        for (int j = 0; j < 8; j += 4) {
            float4 a = *(const float4*)(X + base + g * 8 + j);
            float xs[4] = {a.x, a.y, a.z, a.w};
            #pragma unroll
            for (int q = 0; q < 4; ++q) {
                u16 h = f2bf(xs[q]);
                hv[j + q] = h;
                lv[j + q] = f2bf(xs[q] - bf2f(h));
            }
        }
        *(u16x8*)&H[base + g * 8] = hv;
        *(u16x8*)&L[base + g * 8] = lv;
    }
}

// ---------------------------------------------------------------------------
// Transpose + bf16 (hi only): W[Kd][Nd] fp32 -> OH[Nd][Kd] bf16.
// ---------------------------------------------------------------------------
__global__ __launch_bounds__(256) void splitT_h(const float* __restrict__ W,
                                                u16* __restrict__ OH,
                                                int Kd, int Nd) {
    __shared__ float tile[64][68];
    int k0 = blockIdx.x * 64, n0 = blockIdx.y * 64;
    {
        int r = threadIdx.x >> 2, cg = threadIdx.x & 3;
        const float* src = W + (size_t)(k0 + r) * Nd + n0 + cg * 16;
        #pragma unroll
        for (int j = 0; j < 4; ++j)
            *(float4*)&tile[r][cg * 16 + j * 4] = *(const float4*)(src + j * 4);
    }
    __syncthreads();
    int nl = threadIdx.x >> 2, kg = threadIdx.x & 3;
    u16x8 hv[2];
    #pragma unroll
    for (int j = 0; j < 16; ++j)
        hv[j >> 3][j & 7] = f2bf(tile[kg * 16 + j][nl]);
    size_t off = (size_t)(n0 + nl) * Kd + k0 + kg * 16;
    *(u16x8*)&OH[off]     = hv[0];
    *(u16x8*)&OH[off + 8] = hv[1];
}

// ---------------------------------------------------------------------------
// 8-phase 256x256 split-bf16 MFMA GEMM (round-4 structure, 16x16x32),
// 2-pass: C = (Ah+Al)*Bh, BK=64, NKT=64. 512 thr = 8 waves (2M x 4N),
// per-wave 128x64 out, acc[8][4] f32x4. Chunk-XOR swizzled LDS via
// pre-swizzled global source. NEW: staging addresses hoisted out of the
// K-loop (4 stream bases precomputed; per stage = scalar tau math + 2 gl_lds)
// to kill the per-phase address-calc VALU that capped MfmaUtil at 42%.
// MODE 0: QKV epilogue (RoPE, exp2-scale on Q; K bf16; V transposed).
// MODE 1: plain fp32 store.
// ---------------------------------------------------------------------------
template<int MODE>
__device__ __forceinline__ void g16_body(
    const u16* __restrict__ Ahp, const u16* __restrict__ Alp,
    const u16* __restrict__ Bhp,
    u16* __restrict__ Qh, u16* __restrict__ Ql,
    u16* __restrict__ Kbo, u16* __restrict__ Vto,
    const float* __restrict__ tab, float* __restrict__ Out,
    int bx, int by)
{
    __shared__ __align__(16) u16 SM[66048];   // 129 KiB (GEMM uses first 65536)

    const int tid = threadIdx.x;
    const int w = tid >> 6, ln = tid & 63;
    const int lo4 = ln & 15, hi4 = ln >> 4;
    const int wr = w >> 2, wc = w & 3;          // 2 x 4 wave grid
    const int m0 = bx * 256, n0 = by * 256;
    const int NKT = 64;

    f32x4 acc[8][4];
    #pragma unroll
    for (int i = 0; i < 8; ++i)
        #pragma unroll
        for (int j = 0; j < 4; ++j) acc[i][j] = (f32x4){0.f, 0.f, 0.f, 0.f};

    // ---- hoisted staging state (per thread) ----
    const int r0  = tid >> 3;                       // row 0..63 within half
    const int cs0 = (tid & 7) ^ (r0 & 7);           // pre-swizzled chunk
    const size_t sA0 = (size_t)(m0 + r0) * 2048 + cs0 * 8;
    const size_t sA1 = sA0 + (size_t)128 * 2048;
    const size_t sB0 = (size_t)(n0 + r0) * 2048 + cs0 * 8;
    const size_t sB1 = sB0 + (size_t)128 * 2048;
    const size_t sStep = (size_t)64 * 2048;         // i=1 half (64 rows)
    u16* const dA0 = SM + tid * 8;                  // + c2*16384 ; +8192 for A1
    u16* const dB0 = SM + 32768 + tid * 8;

    auto STAGE_A0 = [&](int tau) {
        if (tau >= NKT) return;
        const u16* pl = (tau < 32) ? Ahp : Alp;
        const size_t o = sA0 + (size_t)(tau & 31) * 64;
        u16* d = dA0 + (tau & 1) * 16384;
        gl_lds16(pl + o, d);
        gl_lds16(pl + o + sStep, d + 4096);
    };
    auto STAGE_A1 = [&](int tau) {
        if (tau >= NKT) return;
        const u16* pl = (tau < 32) ? Ahp : Alp;
        const size_t o = sA1 + (size_t)(tau & 31) * 64;
        u16* d = dA0 + (tau & 1) * 16384 + 8192;
        gl_lds16(pl + o, d);
        gl_lds16(pl + o + sStep, d + 4096);
    };
    auto STAGE_B0 = [&](int tau) {
        if (tau >= NKT) return;
        const size_t o = sB0 + (size_t)(tau & 31) * 64;
        u16* d = dB0 + (tau & 1) * 16384;
        gl_lds16(Bhp + o, d);
        gl_lds16(Bhp + o + sStep, d + 4096);
    };
    auto STAGE_B1 = [&](int tau) {
        if (tau >= NKT) return;
        const size_t o = sB1 + (size_t)(tau & 31) * 64;
        u16* d = dB0 + (tau & 1) * 16384 + 8192;
        gl_lds16(Bhp + o, d);
        gl_lds16(Bhp + o + sStep, d + 4096);
    };

    // ---- prologue: tile0 (A0,A1,B0,B1) + tile1 (A0,A1) ----
    STAGE_A0(0); STAGE_A1(0); STAGE_B0(0); STAGE_B1(0);
    STAGE_A0(1); STAGE_A1(1);
    WAIT_VM4();
    BAR();

    bf8 a03[4][2], a47[4][2], b01[2][2], b23[2][2];
    const int brow0 = (wc & 1) * 64;

    for (int t = 0; t < NKT; ++t) {
        const int c2 = t & 1;
        const u16* Ab = SM + (c2 * 2 + wr) * 8192;
        const u16* Bb = SM + 32768 + (c2 * 2 + (wc >> 1)) * 8192;

        // ---------- P1: read a[0:3], b[0:1]; stage t+1.B0 ----------
        #pragma unroll
        for (int mf = 0; mf < 4; ++mf) {
            int rr = mf * 16 + lo4, s7 = rr & 7;
            a03[mf][0] = *(const bf8*)&Ab[rr * 64 + ((hi4 ^ s7)) * 8];
            a03[mf][1] = *(const bf8*)&Ab[rr * 64 + (((4 + hi4) ^ s7)) * 8];
        }
        #pragma unroll
        for (int nf = 0; nf < 2; ++nf) {
            int rr = brow0 + nf * 16 + lo4, s7 = rr & 7;
            b01[nf][0] = *(const bf8*)&Bb[rr * 64 + ((hi4 ^ s7)) * 8];
            b01[nf][1] = *(const bf8*)&Bb[rr * 64 + (((4 + hi4) ^ s7)) * 8];
        }
        STAGE_B0(t + 1);
        BAR(); WAIT_LGKM0();
        __builtin_amdgcn_s_setprio(1);
        #pragma unroll
        for (int mf = 0; mf < 4; ++mf)
            #pragma unroll
            for (int nf = 0; nf < 2; ++nf) {
                acc[mf][nf] = MFMA(a03[mf][0], b01[nf][0], acc[mf][nf]);
                acc[mf][nf] = MFMA(a03[mf][1], b01[nf][1], acc[mf][nf]);
            }
        __builtin_amdgcn_s_setprio(0);
        BAR();

        // ---------- P2: read a[4:7]; stage t+1.B1 ----------
        #pragma unroll
        for (int mf = 0; mf < 4; ++mf) {
            int rr = 64 + mf * 16 + lo4, s7 = rr & 7;
            a47[mf][0] = *(const bf8*)&Ab[rr * 64 + ((hi4 ^ s7)) * 8];
            a47[mf][1] = *(const bf8*)&Ab[rr * 64 + (((4 + hi4) ^ s7)) * 8];
        }
        STAGE_B1(t + 1);
        BAR(); WAIT_LGKM0();
        __builtin_amdgcn_s_setprio(1);
        #pragma unroll
        for (int mf = 0; mf < 4; ++mf)
            #pragma unroll
            for (int nf = 0; nf < 2; ++nf) {
                acc[4 + mf][nf] = MFMA(a47[mf][0], b01[nf][0], acc[4 + mf][nf]);
                acc[4 + mf][nf] = MFMA(a47[mf][1], b01[nf][1], acc[4 + mf][nf]);
            }
        __builtin_amdgcn_s_setprio(0);
        BAR();

        // ---------- P3: read b[2:3]; stage t+2.A0 ----------
        #pragma unroll
        for (int nf = 0; nf < 2; ++nf) {
            int rr = brow0 + 32 + nf * 16 + lo4, s7 = rr & 7;
            b23[nf][0] = *(const bf8*)&Bb[rr * 64 + ((hi4 ^ s7)) * 8];
            b23[nf][1] = *(const bf8*)&Bb[rr * 64 + (((4 + hi4) ^ s7)) * 8];
        }
        STAGE_A0(t + 2);
        BAR(); WAIT_LGKM0();
        __builtin_amdgcn_s_setprio(1);
        #pragma unroll
        for (int mf = 0; mf < 4; ++mf)
            #pragma unroll
            for (int nf = 0; nf < 2; ++nf) {
                acc[mf][2 + nf] = MFMA(a03[mf][0], b23[nf][0], acc[mf][2 + nf]);
                acc[mf][2 + nf] = MFMA(a03[mf][1], b23[nf][1], acc[mf][2 + nf]);
            }
        __builtin_amdgcn_s_setprio(0);
        BAR();

        // ---------- P4: stage t+2.A1; boundary wait ----------
        STAGE_A1(t + 2);
        BAR();
        __builtin_amdgcn_s_setprio(1);
        #pragma unroll
        for (int mf = 0; mf < 4; ++mf)
            #pragma unroll
            for (int nf = 0; nf < 2; ++nf) {
                acc[4 + mf][2 + nf] = MFMA(a47[mf][0], b23[nf][0], acc[4 + mf][2 + nf]);
                acc[4 + mf][2 + nf] = MFMA(a47[mf][1], b23[nf][1], acc[4 + mf][2 + nf]);
            }
        __builtin_amdgcn_s_setprio(0);
        if (t < NKT - 2)       { WAIT_VM4(); }
        else if (t == NKT - 2) { WAIT_VM0(); }
        BAR();
    }

    // ======================= epilogues =======================
    if (MODE == 1) {
        #pragma unroll
        for (int mf = 0; mf < 8; ++mf)
            #pragma unroll
            for (int r = 0; r < 4; ++r) {
                int m = m0 + wr * 128 + mf * 16 + hi4 * 4 + r;
                float* rowp = Out + (size_t)m * CC + n0 + wc * 64;
                #pragma unroll
                for (int nf = 0; nf < 4; ++nf)
                    rowp[nf * 16 + lo4] = acc[mf][nf][r];
            }
        return;
    }

    const int sec = n0 >> 11;                  // 0=q 1=k 2=v
    const int hh0 = (n0 >> 7) & 15;
    if (sec < 2) {
        #pragma unroll
        for (int mf = 0; mf < 8; ++mf)
            #pragma unroll
            for (int r = 0; r < 4; ++r) {
                int m = m0 + wr * 128 + mf * 16 + hi4 * 4 + r;
                int t = m & 2047, b = m >> 11;
                #pragma unroll
                for (int nf = 0; nf < 4; ++nf) {
                    int nl = wc * 64 + nf * 16 + lo4;
                    int h = hh0 + (nl >> 7), d = nl & 127;
                    float v = acc[mf][nf][r];
                    float o = __shfl_xor(v, 1);
                    const float2 cs2 = *(const float2*)&tab[(((size_t)t << 6) + (d >> 1)) * 2];
                    float rv = (ln & 1) ? (v * cs2.x + o * cs2.y)
                                        : (v * cs2.x - o * cs2.y);
                    size_t off = (((size_t)(b * HH + h)) * TT + t) * DD + d;
                    if (sec == 0) {
                        rv *= SCALE_Q2;      // 1/sqrt(d) * log2(e): exp2 softmax
                        u16 hv = f2bf(rv);
                        Qh[off] = hv;
                        Ql[off] = f2bf(rv - bf2f(hv));
                    } else {
                        Kbo[off] = f2bf(rv);
                    }
                }
            }
    } else {
        // V: bf16, transpose to [bh][d][t] via LDS [256][258] u16.
        BAR();
        #pragma unroll
        for (int mf = 0; mf < 8; ++mf)
            #pragma unroll
            for (int r = 0; r < 4; ++r) {
                int tl = wr * 128 + mf * 16 + hi4 * 4 + r;
                #pragma unroll
                for (int nf = 0; nf < 4; ++nf) {
                    int nl = wc * 64 + nf * 16 + lo4;
                    SM[tl * 258 + nl] = f2bf(acc[mf][nf][r]);
                }
            }
        BAR();
        int nl = tid >> 1, th = tid & 1;
        int head = hh0 + (nl >> 7), d = nl & 127;
        int b = m0 >> 11, t0 = m0 & 2047;
        size_t base = (((size_t)(b * HH + head)) * DD + d) * TT + t0 + th * 128;
        #pragma unroll
        for (int g = 0; g < 16; ++g) {
            u16x8 vv;
            #pragma unroll
            for (int j = 0; j < 8; ++j) vv[j] = SM[(th * 128 + g * 8 + j) * 258 + nl];
            *(u16x8*)&Vto[base + g * 8] = vv;
        }
    }
}

__global__ __launch_bounds__(512, 2) void qkv_g16(
    const u16* __restrict__ Ahp, const u16* __restrict__ Alp,
    const u16* __restrict__ Bhp,
    u16* __restrict__ Qh, u16* __restrict__ Ql,
    u16* __restrict__ Kbo, u16* __restrict__ Vto,
    const float* __restrict__ tab)
{
    g16_body<0>(Ahp, Alp, Bhp, Qh, Ql, Kbo, Vto, tab, nullptr,
                blockIdx.x, blockIdx.y);
}
__global__ __launch_bounds__(512, 2) void proj_g16(
    const u16* __restrict__ Ahp, const u16* __restrict__ Alp,
    const u16* __restrict__ Bhp, float* __restrict__ Out)
{
    g16_body<1>(Ahp, Alp, Bhp, nullptr, nullptr, nullptr, nullptr,
                nullptr, Out, blockIdx.x, blockIdx.y);
}

// ---------------------------------------------------------------------------
// Flash attention: QBLK=128, KVBLK=64, 4 waves x 32 q-rows.
// Round-4 structure + this round: hoisted stageKV addressing, exp2-domain
// softmax (scale*log2e pre-folded into Q), T5 setprio around MFMA clusters.
// ---------------------------------------------------------------------------
__global__ __launch_bounds__(256, 2) void attn128(
    const u16* __restrict__ Qhp, const u16* __restrict__ Qlp,
    const u16* __restrict__ Kb,  const u16* __restrict__ Vt,
    u16* __restrict__ Yh, u16* __restrict__ Yl)
{
    // u16 index map: K0 @0, K1 @8192, V0 @16384, V1 @24576, Ps @32768 (+w*2048)
    __shared__ __align__(16) u16 SM[40960];   // 80 KiB -> 2 blocks/CU

    const int tid = threadIdx.x;
    const int w = tid >> 6, ln = tid & 63;
    const int lo4 = ln & 15, hi4 = ln >> 4;
    const int bx = blockIdx.x;
    const int qt = (bx & 1) ? (15 - (bx >> 1)) : (bx >> 1);   // pair big+small
    const int bh = blockIdx.y;
    const int q0 = qt * 128;
    const int last = 2 * qt + 1;

    // ---- stage Q hi -> SM[0..16384), Q lo -> SM[16384..32768) ----
    {
        const int qSrc0 = ((tid >> 4) * 128) + (((tid & 15) ^ ((tid >> 4) & 7)) * 8);
        const u16* qs = Qhp + ((size_t)bh * TT + q0) * DD + qSrc0;
        const u16* qls = Qlp + ((size_t)bh * TT + q0) * DD + qSrc0;
        u16* qd = SM + tid * 8;
        #pragma unroll
        for (int i = 0; i < 8; ++i) {
            gl_lds16(qs + i * 2048, qd + i * 2048);
            gl_lds16(qls + i * 2048, qd + 16384 + i * 2048);
        }
    }
    WAIT_VM0();
    BAR();
    bf8 qh[2][4], ql[2][4];
    #pragma unroll
    for (int mf = 0; mf < 2; ++mf) {
        int rq = w * 32 + mf * 16 + lo4, s7 = rq & 7;
        #pragma unroll
        for (int ks = 0; ks < 4; ++ks) {
            int ch = (ks * 4 + hi4) ^ s7;
            qh[mf][ks] = *(const bf8*)&SM[rq * 128 + ch * 8];
            ql[mf][ks] = *(const bf8*)&SM[16384 + rq * 128 + ch * 8];
        }
    }
    WAIT_LGKM0();
    BAR();

    // ---- hoisted K/V staging state ----
    const size_t kBase = (size_t)bh * TT * DD;
    const size_t vBase = (size_t)bh * DD * TT;
    const int kSrc0 = ((tid >> 4) * 128) + (((tid & 15) ^ ((tid >> 4) & 7)) * 8);
    const int vSrc0 = ((tid >> 3) * 2048) + (((tid & 7) ^ ((tid >> 3) & 7)) * 8);
    auto stageKV = [&](int kt2, int buf) {
        const u16* ks = Kb + kBase + kt2 * 8192 + kSrc0;
        u16* kd = SM + buf * 8192 + tid * 8;
        #pragma unroll
        for (int i = 0; i < 4; ++i)
            gl_lds16(ks + i * 2048, kd + i * 2048);
        const u16* vs = Vt + vBase + kt2 * 64 + vSrc0;
        u16* vd = SM + 16384 + buf * 8192 + tid * 8;
        #pragma unroll
        for (int i = 0; i < 4; ++i)
            gl_lds16(vs + i * 65536, vd + i * 2048);
    };
    stageKV(0, 0);

    f32x4 O[2][8];
    #pragma unroll
    for (int mf = 0; mf < 2; ++mf)
        #pragma unroll
        for (int i = 0; i < 8; ++i) O[mf][i] = (f32x4){0.f, 0.f, 0.f, 0.f};
    float m_r[2][4], l_r[2][4];
    #pragma unroll
    for (int mf = 0; mf < 2; ++mf)
        #pragma unroll
        for (int r = 0; r < 4; ++r) { m_r[mf][r] = -1e30f; l_r[mf][r] = 0.f; }

    for (int kt = 0; kt <= last; ++kt) {
        const int cur = kt & 1;
        if (kt < last) { stageKV(kt + 1, cur ^ 1); WAIT_VM8(); }
        else           { WAIT_VM0(); }
        BAR();
        const u16* Kcur = &SM[cur * 8192];
        const u16* Vcur = &SM[16384 + cur * 8192];

        // ---- S2 = (Qh+Ql) K^T in log2 domain (scale*log2e folded into Q) ----
        f32x4 sf[2][4];
        __builtin_amdgcn_s_setprio(1);
        #pragma unroll
        for (int nf = 0; nf < 4; ++nf) {
            f32x4 s0 = (f32x4){0.f, 0.f, 0.f, 0.f};
            f32x4 s1 = (f32x4){0.f, 0.f, 0.f, 0.f};
            int kr = nf * 16 + lo4, s7 = kr & 7;
            #pragma unroll
            for (int ks = 0; ks < 4; ++ks) {
                bf8 bb = *(const bf8*)&Kcur[kr * 128 + ((ks * 4 + hi4) ^ s7) * 8];
                s0 = MFMA(qh[0][ks], bb, s0);
                s0 = MFMA(ql[0][ks], bb, s0);
                s1 = MFMA(qh[1][ks], bb, s1);
                s1 = MFMA(ql[1][ks], bb, s1);
            }
            sf[0][nf] = s0; sf[1][nf] = s1;
        }
        __builtin_amdgcn_s_setprio(0);
        if (kt >= 2 * qt) {   // diagonal tiles: causal mask
            #pragma unroll
            for (int mf = 0; mf < 2; ++mf)
                #pragma unroll
                for (int nf = 0; nf < 4; ++nf)
                    #pragma unroll
                    for (int r = 0; r < 4; ++r) {
                        int kg = kt * 64 + nf * 16 + lo4;
                        int qg = q0 + w * 32 + mf * 16 + hi4 * 4 + r;
                        if (kg > qg) sf[mf][nf][r] = -1e30f;
                    }
        }

        // ---- online softmax (exp2 domain) with defer-max (bit-exact skip) ----
        #pragma unroll
        for (int mf = 0; mf < 2; ++mf) {
            float mx[4];
            #pragma unroll
            for (int r = 0; r < 4; ++r) {
                float m2 = fmaxf(fmaxf(sf[mf][0][r], sf[mf][1][r]),
                                 fmaxf(sf[mf][2][r], sf[mf][3][r]));
                m2 = fmaxf(m2, __shfl_xor(m2, 1));
                m2 = fmaxf(m2, __shfl_xor(m2, 2));
                m2 = fmaxf(m2, __shfl_xor(m2, 4));
                m2 = fmaxf(m2, __shfl_xor(m2, 8));
                mx[r] = m2;
            }
            float al[4] = {1.f, 1.f, 1.f, 1.f};
            bool grow = (mx[0] > m_r[mf][0]) || (mx[1] > m_r[mf][1]) ||
                        (mx[2] > m_r[mf][2]) || (mx[3] > m_r[mf][3]);
            if (__any(grow)) {
                #pragma unroll
                for (int r = 0; r < 4; ++r) {
                    float mn = fmaxf(m_r[mf][r], mx[r]);
                    al[r] = exp2f(m_r[mf][r] - mn);
                    m_r[mf][r] = mn;
                }
                #pragma unroll
                for (int nf2 = 0; nf2 < 8; ++nf2)
                    #pragma unroll
                    for (int r = 0; r < 4; ++r) O[mf][nf2][r] *= al[r];
            }
            #pragma unroll
            for (int r = 0; r < 4; ++r) {
                float rs = 0.f;
                #pragma unroll
                for (int nf = 0; nf < 4; ++nf) {
                    float p = exp2f(sf[mf][nf][r] - m_r[mf][r]);
                    sf[mf][nf][r] = p;
                    rs += p;
                }
                rs += __shfl_xor(rs, 1);
                rs += __shfl_xor(rs, 2);
                rs += __shfl_xor(rs, 4);
                rs += __shfl_xor(rs, 8);
                l_r[mf][r] = l_r[mf][r] * al[r] + rs;
            }
        }

        // ---- P -> bf16 -> per-wave swizzled LDS; then O += P V ----
        u16* pw = &SM[32768 + w * 2048];
        #pragma unroll
        for (int mf = 0; mf < 2; ++mf)
            #pragma unroll
            for (int r = 0; r < 4; ++r) {
                int row = mf * 16 + hi4 * 4 + r;
                int sw = (row & 7) << 3;
                #pragma unroll
                for (int nf = 0; nf < 4; ++nf)
                    pw[row * 64 + ((nf * 16 + lo4) ^ sw)] = f2bf(sf[mf][nf][r]);
            }
        bf8 pa[2][2];
        #pragma unroll
        for (int mf = 0; mf < 2; ++mf) {
            int rp = mf * 16 + lo4, s3 = rp & 7;
            pa[mf][0] = *(const bf8*)&pw[rp * 64 + ((hi4 ^ s3) * 8)];
            pa[mf][1] = *(const bf8*)&pw[rp * 64 + (((4 + hi4) ^ s3) * 8)];
        }
        __builtin_amdgcn_s_setprio(1);
        #pragma unroll
        for (int nf2 = 0; nf2 < 8; ++nf2) {
            int vr = nf2 * 16 + lo4, s7 = vr & 7;
            #pragma unroll
            for (int ks = 0; ks < 2; ++ks) {
                bf8 vb = *(const bf8*)&Vcur[vr * 64 + ((ks * 4 + hi4) ^ s7) * 8];
                O[0][nf2] = MFMA(pa[0][ks], vb, O[0][nf2]);
                O[1][nf2] = MFMA(pa[1][ks], vb, O[1][nf2]);
            }
        }
        __builtin_amdgcn_s_setprio(0);
        BAR();   // all reads of buf[cur] done before next prefetch overwrites
    }

    // ---- epilogue: y = O/l as bf16 hi/lo planes ----
    const int b = bh >> 4, h = bh & 15;
    #pragma unroll
    for (int mf = 0; mf < 2; ++mf)
        #pragma unroll
        for (int r = 0; r < 4; ++r) {
            float inv = 1.0f / l_r[mf][r];
            int t = q0 + w * 32 + mf * 16 + hi4 * 4 + r;
            size_t rowo = ((size_t)(b * TT + t)) * CC + h * DD;
            #pragma unroll
            for (int nf2 = 0; nf2 < 8; ++nf2) {
                float val = O[mf][nf2][r] * inv;
                u16 hv = f2bf(val);
                Yh[rowo + nf2 * 16 + lo4] = hv;
                Yl[rowo + nf2 * 16 + lo4] = f2bf(val - bf2f(hv));
            }
        }
}

// ---------------------------------------------------------------------------
extern "C" void kernel_launch(void* const* d_in, const int* in_sizes, int n_in,
                              void* d_out, int out_size, void* d_ws, size_t ws_size,
                              hipStream_t stream)
{
    const float* X     = (const float*)d_in[0];
    const float* Wqkv  = (const float*)d_in[1];
    const float* Wproj = (const float*)d_in[2];

    char* W = (char*)d_ws;
    float* tab = (float*)W;                                   //   1 MiB
    u16* Wqh = (u16*)(W + (1u << 20));                        //  24 MiB
    u16* Wph = Wqh + 12582912;                                //   8 MiB
    u16* Xh  = Wph + 4194304;                                 //  32 MiB
    u16* Xl  = Xh + 16777216;                                 //  32 MiB
    u16* Kb  = Xl + 16777216;                                 //  32 MiB
    u16* Vt  = Kb + 16777216;                                 //  32 MiB  (~161 MiB)

    u16* Qh = (u16*)d_out;          // parked in d_out (dead before proj writes)
    u16* Ql = Qh + 16777216;

    u16* Yh = Xh;   // y planes alias X planes (X dead after QKV gemm)
    u16* Yl = Xl;

    rope_tab_k<<<dim3(2048), 64, 0, stream>>>(tab);
    split_x_k<<<dim3(4096), 256, 0, stream>>>(X, Xh, Xl);
    splitT_h<<<dim3(32, 96), 256, 0, stream>>>(Wqkv, Wqh, 2048, 6144);
    splitT_h<<<dim3(32, 32), 256, 0, stream>>>(Wproj, Wph, 2048, 2048);

    qkv_g16<<<dim3(32, 24), 512, 0, stream>>>(Xh, Xl, Wqh, Qh, Ql, Kb, Vt, tab);
    attn128<<<dim3(16, 64), 256, 0, stream>>>(Qh, Ql, Kb, Vt, Yh, Yl);
    proj_g16<<<dim3(32, 8), 512, 0, stream>>>(Yh, Yl, Wph, (float*)d_out);
}